// Round 6
// baseline (234.928 us; speedup 1.0000x reference)
//
#include <hip/hip_runtime.h>
#include <math.h>

// SNN event model: causal conv (K=8) + LIF scan + outputs (I, z, s, logits).
// Layout: x (32,1,8192) f32, conv_w (64,1,8) f32, raw_tau (64,) f32.
// out = [I (32*64*8192), z (same), s (same), logits (32*8192)] fp32.
//
// Block = 1 wave (lane = feature), grid = (chunk, batch); warm-up WARM steps.
//
// Ledger: R1 no-barrier neutral; R2 4 waves/SIMD neutral (+steps hurt, and
// TS=16's 64B write granules made writes SLOWER); R4 fp32 neutral; R5 LDS
// dbuf pipeline neutral. Kernel pinned at ~87us = 202MB / 2.3 TB/s while
// fill hits 6.4 TB/s on the same buffer => HBM write-granularity bound:
// 128B granules at 32KB stride from 2048 interleaved wave-streams thrash
// HBM row buffers (~35% eff). Compute changes can't move it — matches all
// neutral rounds.
//
// R6: write granule 128B -> 1KB. CHUNK=256; whole chunk's vp buffered in
// LDS (vp-only trick from R5: 64x257x4 = 66KB, 2 blocks/CU); ONE flush per
// block; one store instruction = one full 1KB row segment (64 lanes x
// float4). Logits = running max folded into flush (coalesced 1KB store).
// XCD swizzle: c = (i&7)*4 + (i>>3) gives each XCD 4 consecutive chunks
// per row -> 4KB-contiguous L2 evictions. Steps also drop 459k -> 360k.

#define LL 8192
#define BB 32
#define FF 64
#define KK 8
#define CHUNK 256
#define NCH 32              // LL / CHUNK
#define WARM 96
#define NX (WARM + 7 + CHUNK)  // 359
#define VPW (CHUNK + 1)     // 257 words/row: [0]=carry vp, [1..256]=tile
                            // row stride 257 mod 32 = 1 -> 2-way banks (free)

typedef float f32x4 __attribute__((ext_vector_type(4)));

__global__ __launch_bounds__(64) void snn_kernel(
    const float* __restrict__ x, const float* __restrict__ conv_w,
    const float* __restrict__ raw_tau, float* __restrict__ out)
{
    __shared__ float vp_s[FF][VPW];        // 65792 B
    __shared__ float x_lds[NX + 1];        // 1440 B
    __shared__ float alpha_s[FF];          // 256 B
    __shared__ float ioma_s[FF];           // 256 B   -> ~67.5 KB, 2 blocks/CU

    const int f  = threadIdx.x;            // lane = feature
    const int b  = blockIdx.y;
    const int i  = blockIdx.x;             // raw chunk slot
    // XCD swizzle (wgid%8 = i%8 since gridDim.x%8==0): XCD k owns chunks
    // [4k, 4k+4) -> contiguous 4KB per output row per XCD.
    const int c  = (i & 7) * (NCH / 8) + (i >> 3);
    const int t0 = c * CHUNK;
    const int g0 = t0 - WARM - 7;          // global time of x_lds[0]

    // ---- per-feature weights: unit-norm filter + alpha (fp64 setup) ----
    double wdd[KK];
    double ssum = 0.0;
    #pragma unroll
    for (int k = 0; k < KK; ++k) {
        double wv = (double)conv_w[f * KK + k];
        wdd[k] = wv;
        ssum += wv * wv;
    }
    double nrm = sqrt(ssum);
    if (nrm < 1e-8) nrm = 1e-8;
    double invn = 1.0 / nrm;
    float wf[KK];
    #pragma unroll
    for (int k = 0; k < KK; ++k) wf[k] = (float)(wdd[k] * invn);

    double rt     = (double)raw_tau[f];
    double tau    = log1p(exp(rt)) + 1e-4;  // softplus + eps
    double alphad = exp(-1.0 / tau);
    const float alpha = (float)alphad;
    const float oma   = (float)(1.0 - alphad);
    alpha_s[f] = alpha;
    ioma_s[f]  = (float)(1.0 / (1.0 - alphad));

    // ---- stage 20*x into LDS (zero pad for t<0) ----
    for (int idx = f; idx < NX; idx += 64) {
        int g = g0 + idx;
        x_lds[idx] = (g >= 0) ? (20.0f * x[(size_t)b * LL + g]) : 0.0f;
    }
    // single-wave block: in-order DS pipe, no barrier needed.

    float* outI  = out;
    float* outZ  = out + (size_t)BB * FF * LL;
    float* outS  = out + (size_t)2 * BB * FF * LL;
    float* outLg = out + (size_t)3 * BB * FF * LL;

    float v = 0.0f;

    // ---- warm-up ----
    #pragma unroll 8
    for (int s = 0; s < WARM; ++s) {
        float acc = 0.0f;
        #pragma unroll
        for (int k = 0; k < KK; ++k) acc = fmaf(wf[k], x_lds[s + k], acc);
        float vp = fmaf(alpha, v, oma * acc);
        if (s == WARM - 1) vp_s[f][0] = vp;   // carry: vp at t0-1
        v = (vp >= 0.25f) ? 0.0f : vp;
    }

    // ---- main scan: whole chunk's vp into LDS ----
    #pragma unroll 8
    for (int t = 0; t < CHUNK; ++t) {
        int s = WARM + t;
        float acc = 0.0f;
        #pragma unroll
        for (int k = 0; k < KK; ++k) acc = fmaf(wf[k], x_lds[s + k], acc);
        float vp = fmaf(alpha, v, oma * acc);
        vp_s[f][1 + t] = vp;
        v = (vp >= 0.25f) ? 0.0f : vp;
    }

    // ---- single flush: one store instruction = one full 1KB row segment ----
    // lane f covers times t0+4f .. t0+4f+3 of every feature row.
    const int tq = 4 * f;
    f32x4 mx = { -1e30f, -1e30f, -1e30f, -1e30f };   // running max over features
    #pragma unroll 4
    for (int fr = 0; fr < FF; ++fr) {
        float al = alpha_s[fr];
        float io = ioma_s[fr];
        f32x4 p  = *reinterpret_cast<f32x4*>(&vp_s[fr][1 + tq]); // vp(t..t+3)
        float pm1 = vp_s[fr][tq];                                 // vp(t-1)
        f32x4 vi, vz, vs;
        {   float vprev = (pm1 >= 0.25f) ? 0.0f : pm1;
            vi.x = fmaf(-al, vprev, p.x) * io;
            vz.x = fmaf(15.0f, p.x, -3.75f);
            vs.x = (p.x >= 0.25f) ? 1.0f : 0.0f; }
        {   float vprev = (p.x >= 0.25f) ? 0.0f : p.x;
            vi.y = fmaf(-al, vprev, p.y) * io;
            vz.y = fmaf(15.0f, p.y, -3.75f);
            vs.y = (p.y >= 0.25f) ? 1.0f : 0.0f; }
        {   float vprev = (p.y >= 0.25f) ? 0.0f : p.y;
            vi.z = fmaf(-al, vprev, p.z) * io;
            vz.z = fmaf(15.0f, p.z, -3.75f);
            vs.z = (p.z >= 0.25f) ? 1.0f : 0.0f; }
        {   float vprev = (p.z >= 0.25f) ? 0.0f : p.z;
            vi.w = fmaf(-al, vprev, p.w) * io;
            vz.w = fmaf(15.0f, p.w, -3.75f);
            vs.w = (p.w >= 0.25f) ? 1.0f : 0.0f; }
        mx.x = fmaxf(mx.x, p.x); mx.y = fmaxf(mx.y, p.y);
        mx.z = fmaxf(mx.z, p.z); mx.w = fmaxf(mx.w, p.w);
        size_t base = ((size_t)b * FF + fr) * LL + t0 + tq;
        __builtin_nontemporal_store(vi, reinterpret_cast<f32x4*>(outI + base));
        __builtin_nontemporal_store(vz, reinterpret_cast<f32x4*>(outZ + base));
        __builtin_nontemporal_store(vs, reinterpret_cast<f32x4*>(outS + base));
    }
    // logits: z is monotone in vp -> map the feature-max once.
    f32x4 lg;
    lg.x = fmaf(15.0f, mx.x, -3.75f);
    lg.y = fmaf(15.0f, mx.y, -3.75f);
    lg.z = fmaf(15.0f, mx.z, -3.75f);
    lg.w = fmaf(15.0f, mx.w, -3.75f);
    __builtin_nontemporal_store(lg,
        reinterpret_cast<f32x4*>(outLg + (size_t)b * LL + t0 + tq));
}

extern "C" void kernel_launch(void* const* d_in, const int* in_sizes, int n_in,
                              void* d_out, int out_size, void* d_ws, size_t ws_size,
                              hipStream_t stream) {
    const float* x  = (const float*)d_in[0];
    const float* w  = (const float*)d_in[1];
    const float* rt = (const float*)d_in[2];
    float* out = (float*)d_out;
    dim3 grid(NCH, BB);
    snn_kernel<<<grid, 64, 0, stream>>>(x, w, rt, out);
}

// Round 8
// 220.968 us; speedup vs baseline: 1.0632x; 1.0632x over previous
//
#include <hip/hip_runtime.h>
#include <math.h>

// SNN event model: causal conv (K=8) + LIF scan + outputs (I, z, s, logits).
// out = [I (32*64*8192), z, s, logits (32*8192)] fp32, 202 MB written.
//
// Block = 1 wave (lane = feature), grid = (chunk, batch); warm-up WARM steps.
//
// Ledger: R1 no-barrier 0; R2 4 waves/SIMD 0 (but 64B granules hurt); R4
// fp32 0; R5 dbuf pipeline 0; R6 1KB granules @ 2 blocks/CU REGRESSED
// (flush duty cycle collapsed). Kernel pinned at 2.3 TB/s effective write
// BW vs fill's 6.4 on the same buffer => HBM write-pattern bound.
// R7: granule/occupancy middle point. CHUNK=128, whole-chunk vp in LDS
// (34 KB -> 4 blocks/CU = 1 wave/SIMD), single flush with 512B-contiguous
// row segments (2 rows per 1KB store instruction). Logits = running max in
// flush, coalesced 512B store. Step count identical to R0.
// (R7 bench was an infra failure; this is an unmodified resubmit.)

#define LL 8192
#define BB 32
#define FF 64
#define KK 8
#define CHUNK 128
#define NCH 64              // LL / CHUNK
#define WARM 96
#define NX (WARM + 7 + CHUNK)  // 231
#define VPW 133             // row stride (floats): [0]=carry, [1..128]=chunk;
                            // odd stride -> ds_write column pattern 2-way (free)

typedef float f32x4 __attribute__((ext_vector_type(4)));

__global__ __launch_bounds__(64) void snn_kernel(
    const float* __restrict__ x, const float* __restrict__ conv_w,
    const float* __restrict__ raw_tau, float* __restrict__ out)
{
    __shared__ float vp_s[FF][VPW];        // 34048 B
    __shared__ float x_lds[NX + 1];        // 928 B
    __shared__ float alpha_s[FF];          // 256 B
    __shared__ float ioma_s[FF];           // 256 B   -> ~35.2 KB, 4 blocks/CU

    const int f  = threadIdx.x;            // lane = feature
    const int b  = blockIdx.y;
    const int i  = blockIdx.x;
    // XCD swizzle: XCD k owns 8 consecutive chunks -> contiguous L2 regions.
    const int c  = (i & 7) * (NCH / 8) + (i >> 3);
    const int t0 = c * CHUNK;
    const int g0 = t0 - WARM - 7;          // global time of x_lds[0]

    // ---- per-feature weights: unit-norm filter + alpha (fp64 setup) ----
    double wdd[KK];
    double ssum = 0.0;
    #pragma unroll
    for (int k = 0; k < KK; ++k) {
        double wv = (double)conv_w[f * KK + k];
        wdd[k] = wv;
        ssum += wv * wv;
    }
    double nrm = sqrt(ssum);
    if (nrm < 1e-8) nrm = 1e-8;
    double invn = 1.0 / nrm;
    float wf[KK];
    #pragma unroll
    for (int k = 0; k < KK; ++k) wf[k] = (float)(wdd[k] * invn);

    double rt     = (double)raw_tau[f];
    double tau    = log1p(exp(rt)) + 1e-4;  // softplus + eps
    double alphad = exp(-1.0 / tau);
    const float alpha = (float)alphad;
    const float oma   = (float)(1.0 - alphad);
    alpha_s[f] = alpha;
    ioma_s[f]  = (float)(1.0 / (1.0 - alphad));

    // ---- stage 20*x into LDS (zero pad for t<0) ----
    for (int idx = f; idx < NX; idx += 64) {
        int g = g0 + idx;
        x_lds[idx] = (g >= 0) ? (20.0f * x[(size_t)b * LL + g]) : 0.0f;
    }
    // single-wave block: in-order DS pipe, no barrier needed.

    float* outI  = out;
    float* outZ  = out + (size_t)BB * FF * LL;
    float* outS  = out + (size_t)2 * BB * FF * LL;
    float* outLg = out + (size_t)3 * BB * FF * LL;

    float v = 0.0f;

    // ---- warm-up ----
    #pragma unroll 8
    for (int s = 0; s < WARM; ++s) {
        float acc = 0.0f;
        #pragma unroll
        for (int k = 0; k < KK; ++k) acc = fmaf(wf[k], x_lds[s + k], acc);
        float vp = fmaf(alpha, v, oma * acc);
        if (s == WARM - 1) vp_s[f][0] = vp;   // carry: vp at t0-1
        v = (vp >= 0.25f) ? 0.0f : vp;
    }

    // ---- main scan: whole chunk's vp into LDS ----
    #pragma unroll 8
    for (int t = 0; t < CHUNK; ++t) {
        int s = WARM + t;
        float acc = 0.0f;
        #pragma unroll
        for (int k = 0; k < KK; ++k) acc = fmaf(wf[k], x_lds[s + k], acc);
        float vp = fmaf(alpha, v, oma * acc);
        vp_s[f][1 + t] = vp;
        v = (vp >= 0.25f) ? 0.0f : vp;
    }

    // ---- single flush: each store instr = 2 rows x 512B contiguous ----
    // lanes 0-31 -> row 2*it,   times t0 + 4*(f&31) .. +3
    // lanes 32-63 -> row 2*it+1, same time span
    const int half = f >> 5;
    const int tq   = (f & 31) * 4;
    f32x4 mx = { -1e30f, -1e30f, -1e30f, -1e30f };   // running max over my rows
    #pragma unroll 4
    for (int it = 0; it < 32; ++it) {
        int fr = 2 * it + half;
        float al = alpha_s[fr];
        float io = ioma_s[fr];
        f32x4 p  = *reinterpret_cast<f32x4*>(&vp_s[fr][1 + tq]); // vp(t..t+3)
        float pm1 = vp_s[fr][tq];                                 // vp(t-1)
        f32x4 vi, vz, vs;
        {   float vprev = (pm1 >= 0.25f) ? 0.0f : pm1;
            vi.x = fmaf(-al, vprev, p.x) * io;
            vz.x = fmaf(15.0f, p.x, -3.75f);
            vs.x = (p.x >= 0.25f) ? 1.0f : 0.0f; }
        {   float vprev = (p.x >= 0.25f) ? 0.0f : p.x;
            vi.y = fmaf(-al, vprev, p.y) * io;
            vz.y = fmaf(15.0f, p.y, -3.75f);
            vs.y = (p.y >= 0.25f) ? 1.0f : 0.0f; }
        {   float vprev = (p.y >= 0.25f) ? 0.0f : p.y;
            vi.z = fmaf(-al, vprev, p.z) * io;
            vz.z = fmaf(15.0f, p.z, -3.75f);
            vs.z = (p.z >= 0.25f) ? 1.0f : 0.0f; }
        {   float vprev = (p.z >= 0.25f) ? 0.0f : p.z;
            vi.w = fmaf(-al, vprev, p.w) * io;
            vz.w = fmaf(15.0f, p.w, -3.75f);
            vs.w = (p.w >= 0.25f) ? 1.0f : 0.0f; }
        mx.x = fmaxf(mx.x, p.x); mx.y = fmaxf(mx.y, p.y);
        mx.z = fmaxf(mx.z, p.z); mx.w = fmaxf(mx.w, p.w);
        size_t base = ((size_t)b * FF + fr) * LL + t0 + tq;
        __builtin_nontemporal_store(vi, reinterpret_cast<f32x4*>(outI + base));
        __builtin_nontemporal_store(vz, reinterpret_cast<f32x4*>(outZ + base));
        __builtin_nontemporal_store(vs, reinterpret_cast<f32x4*>(outS + base));
    }
    // logits: lanes f and f^32 hold complementary row sets at the same times.
    mx.x = fmaxf(mx.x, __shfl_xor(mx.x, 32));
    mx.y = fmaxf(mx.y, __shfl_xor(mx.y, 32));
    mx.z = fmaxf(mx.z, __shfl_xor(mx.z, 32));
    mx.w = fmaxf(mx.w, __shfl_xor(mx.w, 32));
    if (half == 0) {
        f32x4 lg;
        lg.x = fmaf(15.0f, mx.x, -3.75f);
        lg.y = fmaf(15.0f, mx.y, -3.75f);
        lg.z = fmaf(15.0f, mx.z, -3.75f);
        lg.w = fmaf(15.0f, mx.w, -3.75f);
        __builtin_nontemporal_store(lg,
            reinterpret_cast<f32x4*>(outLg + (size_t)b * LL + t0 + tq));
    }
}

extern "C" void kernel_launch(void* const* d_in, const int* in_sizes, int n_in,
                              void* d_out, int out_size, void* d_ws, size_t ws_size,
                              hipStream_t stream) {
    const float* x  = (const float*)d_in[0];
    const float* w  = (const float*)d_in[1];
    const float* rt = (const float*)d_in[2];
    float* out = (float*)d_out;
    dim3 grid(NCH, BB);
    snn_kernel<<<grid, 64, 0, stream>>>(x, w, rt, out);
}

// Round 9
// 215.494 us; speedup vs baseline: 1.0902x; 1.0254x over previous
//
#include <hip/hip_runtime.h>
#include <math.h>

// SNN event model: causal conv (K=8) + LIF scan + outputs (I, z, s, logits).
// out = [I (32,64,8192), z, s, logits (32,8192)] fp32, ~202 MB written.
//
// Block = 1 wave (lane = feature), grid = (chunk=128, batch); warm-up WARM.
//
// Ledger: R1 no-barrier 0; R2 +steps => +18us (=> step-work ~42us @ baseline);
// R4 fp32 0; R5 separate-loop dbuf 0; R6/R8 big-granule + low-occupancy NEG
// (granule axis falsified). Decomposition: kernel ~86us = scan ~42 + stores
// ~31 (at full BW) + overhead: phases SERIALIZE because in-phase blocks only
// issue stores during flush windows (~25% duty).
// R9: manual 1:1 scan||flush interleave — each scan step of tile k flushes one
// row-pair of tile k-1 (3 scalar stores/step, evenly spread; vp double-buffer
// from R5 gives hazard-free overlap). Store-active duty 25% -> ~57%.
// Also: x window register-rotated (2 broadcast ds_read_b128 per 8 steps
// instead of ~8 ds_read_b32/step), WARM 96->64 (alpha^64 <= 1.3e-8 carry
// error, below fp32 noise; revert to 96 if validation fails).

#define LL 8192
#define BB 32
#define FF 64
#define KK 8
#define CHUNK 128
#define NCH 64              // LL / CHUNK
#define WARM 64
#define NX (WARM + 7 + CHUNK)  // 199
#define TS 32               // timesteps per tile
#define NT (CHUNK / TS)     // 4
#define ROWW (TS + 1)       // 33 floats: [0]=carry vp, [1..32]=tile (odd: banks ok)

typedef float f32x4 __attribute__((ext_vector_type(4)));

__global__ __launch_bounds__(64) void snn_kernel(
    const float* __restrict__ x, const float* __restrict__ conv_w,
    const float* __restrict__ raw_tau, float* __restrict__ out)
{
    __shared__ __align__(16) float x_lds[NX + 9];  // +8 prefetch slack (zeroed)
    __shared__ float bufA[FF][ROWW];               // 8448 B
    __shared__ float bufB[FF][ROWW];               // 8448 B
    __shared__ float alpha_s[FF];
    __shared__ float ioma_s[FF];                   // total ~18.2 KB -> 8 blk/CU

    const int f    = threadIdx.x;                  // lane = feature (scan role)
    const int b    = blockIdx.y;
    const int c    = blockIdx.x;
    const int t0   = c * CHUNK;
    const int g0   = t0 - WARM - 7;                // global time of x_lds[0]
    const int tl   = f & 31;                       // time-in-tile (flush role)
    const int half = f >> 5;                       // row parity (flush role)

    // ---- per-feature weights: unit-norm filter + alpha (fp64 setup) ----
    double wdd[KK];
    double ssum = 0.0;
    #pragma unroll
    for (int k = 0; k < KK; ++k) {
        double wv = (double)conv_w[f * KK + k];
        wdd[k] = wv;
        ssum += wv * wv;
    }
    double nrm = sqrt(ssum);
    if (nrm < 1e-8) nrm = 1e-8;
    double invn = 1.0 / nrm;
    float wf[KK];
    #pragma unroll
    for (int k = 0; k < KK; ++k) wf[k] = (float)(wdd[k] * invn);

    double rt     = (double)raw_tau[f];
    double tau    = log1p(exp(rt)) + 1e-4;  // softplus + eps
    double alphad = exp(-1.0 / tau);
    const float alpha_f = (float)alphad;
    const float oma     = (float)(1.0 - alphad);
    alpha_s[f] = alpha_f;
    ioma_s[f]  = (float)(1.0 / (1.0 - alphad));

    // ---- stage 20*x into LDS (zero pad for t<0; zero the prefetch slack) ----
    for (int i = f; i < NX + 8; i += 64) {
        int g = g0 + i;
        x_lds[i] = (i < NX && g >= 0) ? (20.0f * x[(size_t)b * LL + g]) : 0.0f;
    }
    // single-wave block: in-order DS pipe, no barrier needed.

    float* outI  = out;
    float* outZ  = out + (size_t)BB * FF * LL;
    float* outS  = out + (size_t)2 * BB * FF * LL;
    float* outLg = out + (size_t)3 * BB * FF * LL;

    float v = 0.0f, vp_last = 0.0f;
    float xw[16];                         // rotating x window (wave-uniform)
    {
        f32x4 a  = *(const f32x4*)&x_lds[0];
        f32x4 b4 = *(const f32x4*)&x_lds[4];
        xw[0]=a.x; xw[1]=a.y; xw[2]=a.z; xw[3]=a.w;
        xw[4]=b4.x; xw[5]=b4.y; xw[6]=b4.z; xw[7]=b4.w;
    }
    #define LOAD8(base) do { \
        f32x4 _a  = *(const f32x4*)&x_lds[(base)];     \
        f32x4 _b4 = *(const f32x4*)&x_lds[(base) + 4]; \
        xw[8]=_a.x; xw[9]=_a.y; xw[10]=_a.z; xw[11]=_a.w; \
        xw[12]=_b4.x; xw[13]=_b4.y; xw[14]=_b4.z; xw[15]=_b4.w; } while (0)
    #define SHIFT8() do { _Pragma("unroll") \
        for (int _i = 0; _i < 8; ++_i) xw[_i] = xw[_i + 8]; } while (0)
    #define SCAN_STEP(J) \
        float acc = 0.0f; \
        _Pragma("unroll") \
        for (int _k = 0; _k < KK; ++_k) acc = fmaf(wf[_k], xw[(J) + _k], acc); \
        float vp = fmaf(alpha_f, v, oma * acc); \
        vp_last = vp; \
        v = (vp >= 0.25f) ? 0.0f : vp;

    // ---- warm-up (no flush partner) ----
    #pragma unroll
    for (int m = 0; m < WARM / 8; ++m) {
        LOAD8(8 * m + 8);
        #pragma unroll
        for (int j = 0; j < 8; ++j) { SCAN_STEP(j); }
        SHIFT8();
    }

    // ---- tile 0 scan (no flush partner) ----
    bufA[f][0] = vp_last;
    #pragma unroll
    for (int m = 0; m < 4; ++m) {
        LOAD8(WARM + 8 * m + 8);
        #pragma unroll
        for (int j = 0; j < 8; ++j) {
            SCAN_STEP(j);
            bufA[f][1 + 8 * m + j] = vp;
        }
        SHIFT8();
    }

    float mx;
    // ---- interleaved: scan tile k into cur, flush tile k-1 from prev ----
    auto tile_scan_flush = [&](int k, float (*cur)[ROWW], float (*prev)[ROWW]) {
        cur[f][0] = vp_last;
        const int gtp = t0 + (k - 1) * TS;
        mx = -1e30f;
        #pragma unroll
        for (int m = 0; m < 4; ++m) {
            LOAD8(WARM + k * TS + 8 * m + 8);
            #pragma unroll
            for (int j = 0; j < 8; ++j) {
                {   SCAN_STEP(j);
                    cur[f][1 + 8 * m + j] = vp;
                }
                // flush row-pair q of the PREVIOUS tile (other buffer)
                int   q   = 8 * m + j;
                int   row = 2 * q + half;
                float pb  = prev[row][1 + tl];     // vp(t)
                float pm  = prev[row][tl];         // vp(t-1) ([0] = carry)
                float al  = alpha_s[row];
                float io2 = ioma_s[row];
                float vprev = (pm >= 0.25f) ? 0.0f : pm;
                float Iv = fmaf(-al, vprev, pb) * io2;
                float zv = fmaf(15.0f, pb, -3.75f);
                float sv = (pb >= 0.25f) ? 1.0f : 0.0f;
                size_t basep = ((size_t)b * FF + row) * LL + gtp + tl;
                __builtin_nontemporal_store(Iv, outI + basep);
                __builtin_nontemporal_store(zv, outZ + basep);
                __builtin_nontemporal_store(sv, outS + basep);
                mx = fmaxf(mx, pb);
            }
            SHIFT8();
        }
        // logits of tile k-1: even-rows max (lanes<32) vs odd-rows (lanes>=32)
        float m2 = fmaxf(mx, __shfl_xor(mx, 32));
        if (half == 0)
            __builtin_nontemporal_store(fmaf(15.0f, m2, -3.75f),
                                        outLg + (size_t)b * LL + gtp + tl);
    };
    tile_scan_flush(1, bufB, bufA);
    tile_scan_flush(2, bufA, bufB);
    tile_scan_flush(3, bufB, bufA);

    // ---- epilogue: flush tile 3 (no scan partner) ----
    {
        const int gtp = t0 + 3 * TS;
        mx = -1e30f;
        #pragma unroll
        for (int q = 0; q < 32; ++q) {
            int   row = 2 * q + half;
            float pb  = bufB[row][1 + tl];
            float pm  = bufB[row][tl];
            float al  = alpha_s[row];
            float io2 = ioma_s[row];
            float vprev = (pm >= 0.25f) ? 0.0f : pm;
            float Iv = fmaf(-al, vprev, pb) * io2;
            float zv = fmaf(15.0f, pb, -3.75f);
            float sv = (pb >= 0.25f) ? 1.0f : 0.0f;
            size_t basep = ((size_t)b * FF + row) * LL + gtp + tl;
            __builtin_nontemporal_store(Iv, outI + basep);
            __builtin_nontemporal_store(zv, outZ + basep);
            __builtin_nontemporal_store(sv, outS + basep);
            mx = fmaxf(mx, pb);
        }
        float m2 = fmaxf(mx, __shfl_xor(mx, 32));
        if (half == 0)
            __builtin_nontemporal_store(fmaf(15.0f, m2, -3.75f),
                                        outLg + (size_t)b * LL + gtp + tl);
    }
}

extern "C" void kernel_launch(void* const* d_in, const int* in_sizes, int n_in,
                              void* d_out, int out_size, void* d_ws, size_t ws_size,
                              hipStream_t stream) {
    const float* x  = (const float*)d_in[0];
    const float* w  = (const float*)d_in[1];
    const float* rt = (const float*)d_in[2];
    float* out = (float*)d_out;
    dim3 grid(NCH, BB);
    snn_kernel<<<grid, 64, 0, stream>>>(x, w, rt, out);
}